// Round 5
// baseline (332.457 us; speedup 1.0000x reference)
//
#include <hip/hip_runtime.h>
#include <hip/hip_bf16.h>

// Problem: B=4, N=2048, IN=256, H=8, ATN=32
//   xt = x@W + b; xC = xt@C^T; S = xC@xt^T; alpha = tanh(S*adj);
//   out = concat_h(alpha @ xt)  [B,N,256] fp32
//
// R13: R12 post-mortem — XCD grouping cut FETCH 70->42MB but dur unchanged:
// L2 misses were never the critical path. 73us floor is invariant under
// barrier count, VALU cut, L2 locality -> the binder is the lockstep
// skeleton itself: vmcnt retires IN ORDER and the per-tile reg loads share
// the counter with the adj DMAs, so each COMPUTE's operand wait forces
// retirement of a DMA issued ~1 step earlier (effective prefetch depth
// ~1.5 tiles, ~KBs in flight per CU, adj delivered at 860GB/s); barriers
// phase-lock all waves into issue-then-drain bursts. R9 tested "no
// skeleton" but the compiler sank the loads (VGPR 40 = depth 0).
// R13 = R9 structure with the R5-proven pinning kept: no LDS, no barrier,
// no manual vmcnt; ONE sched_barrier(0) per tile + full-unroll 3-slot
// named register rotation (cur/nxt/fut) = strict depth-2 prefetch of ALL
// operands (adj as per-lane f32x4, mapping correctness-proven in R9).
// Per-wave homogeneous vmem stream -> in-order retirement harmless; waves
// free-run; 8 heads share adj tiles via L1/L2 (XCD grouping kept).
// 256-thr blocks (4 waves, head = hg*4+wave), launch_bounds(256,4) caps
// VGPR at 128. Epilogue/slabs/k_reduce/k_prep/k_proj: frozen R12.

typedef __bf16 bf16;
typedef __attribute__((ext_vector_type(8))) __bf16 bf16x8;
typedef __attribute__((ext_vector_type(4))) __bf16 bf16x4;
typedef __attribute__((ext_vector_type(4))) float  f32x4;

#define MFMA(a, b, c) __builtin_amdgcn_mfma_f32_16x16x32_bf16(a, b, c, 0, 0, 0)
#define FENCE()   __builtin_amdgcn_sched_barrier(0)

// Exact tanh via exp2 (3 VALU + 2 trans): 1 - 2/(e^{2x}+1).
// R10-validated: exact, saturates, absmax unchanged.
__device__ __forceinline__ float fast_tanh(float x) {
    float e = __builtin_amdgcn_exp2f(x * 2.88539008177792681f);  // 2*log2(e)
    float r = __builtin_amdgcn_rcpf(e + 1.0f);
    return __builtin_fmaf(-2.0f, r, 1.0f);
}

#define BB   4
#define NN   2048
#define IND  256
#define HH   8
#define ATN  32

// workspace layout (bytes) — total 25.3 MB (proven footprint)
#define OFF_XBF   0u           // x bf16 (4 MB); DEAD after k_proj -> reused as slab0
#define OFF_XT    4194304u
#define OFF_XC    8388608u
#define OFF_XTT   12582912u
#define OFF_WT    16777216u
#define OFF_CB    16908288u
#define OFF_SLAB  16924672u    // slab1 (4 MB bf16) + slab2 (4 MB bf16)

// ---------------- kernel 0: dtype conversion ----------------
__global__ __launch_bounds__(256) void k_prep(const float* __restrict__ x,
                                              const float* __restrict__ W,
                                              const float* __restrict__ C,
                                              bf16* __restrict__ xbf,
                                              bf16* __restrict__ WT,
                                              bf16* __restrict__ Cb) {
    int tid = blockIdx.x * 256 + threadIdx.x;
    if (tid < 524288) {
        float4 v = ((const float4*)x)[tid];
        bf16x4 o;
        o[0] = (bf16)v.x; o[1] = (bf16)v.y; o[2] = (bf16)v.z; o[3] = (bf16)v.w;
        *(bf16x4*)(xbf + (size_t)tid * 4) = o;
    } else if (tid < 524288 + 65536) {
        int t = tid - 524288;
        int h = t >> 13, r = t & 8191, i = r >> 5, o = r & 31;
        WT[(h * 32 + o) * 256 + i] = (bf16)W[t];
    } else if (tid < 524288 + 65536 + 8192) {
        int t = tid - (524288 + 65536);
        Cb[t] = (bf16)C[t];
    }
}

// ---------------- kernel A: projection ----------------
__global__ __launch_bounds__(256) void k_proj(const bf16* __restrict__ xbf,
                                              const bf16* __restrict__ WT,
                                              const bf16* __restrict__ Cb,
                                              const float* __restrict__ bias,
                                              bf16* __restrict__ xt,
                                              bf16* __restrict__ xc,
                                              bf16* __restrict__ xtT) {
    __shared__ bf16 ldsA_all[4][32 * 40];
    __shared__ bf16 ldsB_all[4][32 * 40];
    int bid = blockIdx.x;
    int ntg = bid & 15, h = (bid >> 4) & 7, b = bid >> 7;
    int wave = threadIdx.x >> 6;
    int lane = threadIdx.x & 63;
    int nt = ntg * 4 + wave;
    int n0 = nt * 32;
    int c = lane & 15, q = lane >> 4;
    bf16* ldsA = ldsA_all[wave];
    bf16* ldsB = ldsB_all[wave];

    f32x4 acc[2][2] = {};
    const bf16* xrow0 = xbf + ((size_t)(b * NN + n0 + c) * IND + q * 8);
    const bf16* xrow1 = xbf + ((size_t)(b * NN + n0 + 16 + c) * IND + q * 8);
    const bf16* wrow0 = WT + ((h * 32 + c) * IND + q * 8);
    const bf16* wrow1 = WT + ((h * 32 + 16 + c) * IND + q * 8);
#pragma unroll
    for (int k0 = 0; k0 < IND; k0 += 32) {
        bf16x8 a0 = *(const bf16x8*)(xrow0 + k0);
        bf16x8 a1 = *(const bf16x8*)(xrow1 + k0);
        bf16x8 w0 = *(const bf16x8*)(wrow0 + k0);
        bf16x8 w1 = *(const bf16x8*)(wrow1 + k0);
        acc[0][0] = MFMA(a0, w0, acc[0][0]);
        acc[0][1] = MFMA(a0, w1, acc[0][1]);
        acc[1][0] = MFMA(a1, w0, acc[1][0]);
        acc[1][1] = MFMA(a1, w1, acc[1][1]);
    }
    float bv[2] = { bias[h * 32 + c], bias[h * 32 + 16 + c] };
    size_t bh = (size_t)(b * HH + h);
#pragma unroll
    for (int nq = 0; nq < 2; ++nq)
#pragma unroll
        for (int oq = 0; oq < 2; ++oq)
#pragma unroll
            for (int r = 0; r < 4; ++r)
                ldsA[(nq * 16 + q * 4 + r) * 40 + oq * 16 + c] =
                    (bf16)(acc[nq][oq][r] + bv[oq]);
    f32x4 acc2[2][2] = {};
    bf16x8 aL0 = *(const bf16x8*)(ldsA + (c) * 40 + q * 8);
    bf16x8 aL1 = *(const bf16x8*)(ldsA + (16 + c) * 40 + q * 8);
    bf16x8 c0 = *(const bf16x8*)(Cb + h * 1024 + (c) * 32 + q * 8);
    bf16x8 c1 = *(const bf16x8*)(Cb + h * 1024 + (16 + c) * 32 + q * 8);
    acc2[0][0] = MFMA(aL0, c0, acc2[0][0]);
    acc2[0][1] = MFMA(aL0, c1, acc2[0][1]);
    acc2[1][0] = MFMA(aL1, c0, acc2[1][0]);
    acc2[1][1] = MFMA(aL1, c1, acc2[1][1]);
#pragma unroll
    for (int nq = 0; nq < 2; ++nq)
#pragma unroll
        for (int pq = 0; pq < 2; ++pq)
#pragma unroll
            for (int r = 0; r < 4; ++r)
                ldsB[(nq * 16 + q * 4 + r) * 40 + pq * 16 + c] =
                    (bf16)acc2[nq][pq][r];

    {   // coalesced xt/xc stores
        int n = lane >> 1, half = lane & 1;
        bf16x8 t0 = *(const bf16x8*)(ldsA + n * 40 + half * 16);
        bf16x8 t1 = *(const bf16x8*)(ldsA + n * 40 + half * 16 + 8);
        bf16* dst = xt + (bh * NN + n0 + n) * ATN + half * 16;
        *(bf16x8*)(dst) = t0;
        *(bf16x8*)(dst + 8) = t1;
        bf16x8 u0 = *(const bf16x8*)(ldsB + n * 40 + half * 16);
        bf16x8 u1 = *(const bf16x8*)(ldsB + n * 40 + half * 16 + 8);
        bf16* dst2 = xc + (bh * NN + n0 + n) * ATN + half * 16;
        *(bf16x8*)(dst2) = u0;
        *(bf16x8*)(dst2 + 8) = u1;
    }
    {   // xtT via LDS-gathered transpose
        int o = lane >> 1, nh = lane & 1;
        bf16x8 t0, t1;
#pragma unroll
        for (int i = 0; i < 8; ++i) {
            t0[i] = ldsA[(nh * 16 + i) * 40 + o];
            t1[i] = ldsA[(nh * 16 + 8 + i) * 40 + o];
        }
        bf16* dst = xtT + (bh * ATN + o) * NN + n0 + nh * 16;
        *(bf16x8*)(dst) = t0;
        *(bf16x8*)(dst + 8) = t1;
    }
}

// ---------------- kernel B: fused scores/tanh/PV, barrier-free ----------------
// grid 2048 = 16 groups x 128 members; XCD-grouped: L = mem*16 + g,
// g = chunk*4 + b (kept from R12: FETCH -40%, harmless).
// 256 thr = 4 waves; member = nt*2 + hg; head = hg*4 + wave.
// No LDS / no barrier / no manual vmcnt. Depth-2 prefetch of ALL operands
// via full-unroll 3-slot named rotation, pinned by one sched_barrier(0)
// per tile. adj fragments loaded per-lane (mapping verified in R9):
// A00[j]=adj[n0+c][m0+8q+j], A01 next 16B, A10/A11 at row n0+16+c.
__global__ __launch_bounds__(256, 4) void k_attn(const float* __restrict__ adj,
                                                 const bf16* __restrict__ xt,
                                                 const bf16* __restrict__ xc,
                                                 const bf16* __restrict__ xtT,
                                                 bf16* __restrict__ sl0,
                                                 bf16* __restrict__ sl1,
                                                 bf16* __restrict__ sl2,
                                                 float* __restrict__ out) {
    int L = blockIdx.x;
    int g = L & 15;                         // XCD group id: (chunk,b)
    int mem = L >> 4;                       // member 0..127
    int chunk = g >> 2, b = g & 3;
    int nt = mem >> 1, hg = mem & 1;
    int n0 = nt * 32;
    int wave = threadIdx.x >> 6;            // 0..3
    int head = hg * 4 + wave;
    int lane = threadIdx.x & 63;
    int c = lane & 15, q = lane >> 4;
    int p = 8 * (c >> 2) + (c & 3);         // S A-row permutation
    size_t bh = (size_t)(b * HH + head);
    const bf16* xt_h = xt + bh * NN * ATN;
    const bf16* xc_h = xc + bh * NN * ATN;
    const bf16* xtT_h = xtT + bh * ATN * NN;
    const float* adj_b = adj + (size_t)b * NN * NN;
    const int m_beg = chunk * 512;          // 16 tiles of 32

    // per-lane adj row bases (R9-verified mapping)
    const float* aR0 = adj_b + (size_t)(n0 + c) * NN + m_beg + q * 8;
    const float* aR1 = adj_b + (size_t)(n0 + 16 + c) * NN + m_beg + q * 8;

    bf16x8 bXC0 = *(const bf16x8*)(xc_h + (n0 + c) * ATN + q * 8);
    bf16x8 bXC1 = *(const bf16x8*)(xc_h + (n0 + 16 + c) * ATN + q * 8);
    f32x4 accO[2][2] = {};                  // O^T [oq][nq]
    const f32x4 z = {0.f, 0.f, 0.f, 0.f};

    struct Tile {
        f32x4 A00, A01, A10, A11;
        bf16x8 xA0, xA1, oA0, oA1;
    };

#define LOAD(t) [&]{ Tile T_;                                                  \
        int m0 = m_beg + (t) * 32;                                             \
        T_.A00 = *(const f32x4*)(aR0 + (t) * 32);                              \
        T_.A01 = *(const f32x4*)(aR0 + (t) * 32 + 4);                          \
        T_.A10 = *(const f32x4*)(aR1 + (t) * 32);                              \
        T_.A11 = *(const f32x4*)(aR1 + (t) * 32 + 4);                          \
        T_.xA0 = *(const bf16x8*)(xt_h + (size_t)(m0 + p) * ATN + q * 8);      \
        T_.xA1 = *(const bf16x8*)(xt_h + (size_t)(m0 + p + 4) * ATN + q * 8);  \
        T_.oA0 = *(const bf16x8*)(xtT_h + (size_t)(c) * NN + m0 + q * 8);      \
        T_.oA1 = *(const bf16x8*)(xtT_h + (size_t)(16 + c) * NN + m0 + q * 8); \
        return T_; }()

#define COMPUTE(T) do {                                                        \
        f32x4 S0a = MFMA(T.xA0, bXC0, z);   /* S[m0+8q+r  ][n0+c]    */        \
        f32x4 S0b = MFMA(T.xA1, bXC0, z);   /* S[m0+8q+4+r][n0+c]    */        \
        f32x4 S1a = MFMA(T.xA0, bXC1, z);   /* S[m0+8q+r  ][n0+16+c] */        \
        f32x4 S1b = MFMA(T.xA1, bXC1, z);                                      \
        bf16x8 P0, P1;                                                         \
        _Pragma("unroll") for (int r = 0; r < 4; ++r) {                        \
            P0[r]     = (bf16)fast_tanh(S0a[r] * T.A00[r]);                    \
            P0[4 + r] = (bf16)fast_tanh(S0b[r] * T.A01[r]);                    \
            P1[r]     = (bf16)fast_tanh(S1a[r] * T.A10[r]);                    \
            P1[4 + r] = (bf16)fast_tanh(S1b[r] * T.A11[r]);                    \
        }                                                                      \
        accO[0][0] = MFMA(T.oA0, P0, accO[0][0]);                              \
        accO[0][1] = MFMA(T.oA0, P1, accO[0][1]);                              \
        accO[1][0] = MFMA(T.oA1, P0, accO[1][0]);                              \
        accO[1][1] = MFMA(T.oA1, P1, accO[1][1]);                              \
    } while (0)

    // ---- barrier-free pipeline: depth-2 named rotation, fence-pinned ----
    Tile cur = LOAD(0);
    Tile nxt = LOAD(1);
#pragma unroll
    for (int t = 0; t < 16; ++t) {
        Tile fut = nxt;                     // dummy init; overwritten below
        if (t + 2 < 16) {
            switch (t + 2) {                // compile-time t under full unroll
            case 2:  fut = LOAD(2);  break;  case 3:  fut = LOAD(3);  break;
            case 4:  fut = LOAD(4);  break;  case 5:  fut = LOAD(5);  break;
            case 6:  fut = LOAD(6);  break;  case 7:  fut = LOAD(7);  break;
            case 8:  fut = LOAD(8);  break;  case 9:  fut = LOAD(9);  break;
            case 10: fut = LOAD(10); break;  case 11: fut = LOAD(11); break;
            case 12: fut = LOAD(12); break;  case 13: fut = LOAD(13); break;
            case 14: fut = LOAD(14); break;  default: fut = LOAD(15); break;
            }
        }
        FENCE();                            // loads(t+2) pinned before compute(t)
        COMPUTE(cur);
        cur = nxt; nxt = fut;
    }

#undef LOAD
#undef COMPUTE

    // epilogue: O^T: o = head*32 + oq*16 + 4q + r, n = n0 + nq*16 + c.
    // chunk 3 -> f32 out; chunks 0-2 -> bf16 slabs; k_reduce sums.
    if (chunk == 3) {
#pragma unroll
        for (int oq = 0; oq < 2; ++oq)
#pragma unroll
            for (int nq = 0; nq < 2; ++nq) {
                size_t n = n0 + nq * 16 + c;
                *(f32x4*)&out[((size_t)b * NN + n) * 256 + head * 32 + oq * 16 + 4 * q] =
                    accO[oq][nq];
            }
    } else {
        bf16* sl = (chunk == 0) ? sl0 : (chunk == 1 ? sl1 : sl2);
#pragma unroll
        for (int oq = 0; oq < 2; ++oq)
#pragma unroll
            for (int nq = 0; nq < 2; ++nq) {
                size_t n = n0 + nq * 16 + c;
                bf16x4 v;
#pragma unroll
                for (int r = 0; r < 4; ++r) v[r] = (bf16)accO[oq][nq][r];
                *(bf16x4*)&sl[((size_t)b * NN + n) * 256 + head * 32 + oq * 16 + 4 * q] = v;
            }
    }
}

// ---------------- kernel C: out += sl0 + sl1 + sl2 ----------------
__global__ __launch_bounds__(256) void k_reduce(const bf16* __restrict__ sl0,
                                                const bf16* __restrict__ sl1,
                                                const bf16* __restrict__ sl2,
                                                float* __restrict__ out) {
    int i = blockIdx.x * 256 + threadIdx.x;   // f32x4 index, 524288 total
    f32x4 a = ((const f32x4*)out)[i];
    bf16x4 s0 = ((const bf16x4*)sl0)[i];
    bf16x4 s1 = ((const bf16x4*)sl1)[i];
    bf16x4 s2 = ((const bf16x4*)sl2)[i];
#pragma unroll
    for (int r = 0; r < 4; ++r)
        a[r] += (float)s0[r] + (float)s1[r] + (float)s2[r];
    ((f32x4*)out)[i] = a;
}

extern "C" void kernel_launch(void* const* d_in, const int* in_sizes, int n_in,
                              void* d_out, int out_size, void* d_ws, size_t ws_size,
                              hipStream_t stream) {
    const float* x    = (const float*)d_in[0];   // [4,2048,256]
    const float* adj  = (const float*)d_in[1];   // [4,2048,2048]
    const float* W    = (const float*)d_in[2];   // [8,256,32]
    const float* bias = (const float*)d_in[3];   // [8,32]
    const float* C    = (const float*)d_in[4];   // [8,32,32]
    float* out = (float*)d_out;                  // [4,2048,256]

    char* ws = (char*)d_ws;                      // 25.3 MB (proven footprint)
    bf16*  xbf  = (bf16*)(ws + OFF_XBF);         // dead after k_proj -> slab0
    bf16*  xt   = (bf16*)(ws + OFF_XT);
    bf16*  xc   = (bf16*)(ws + OFF_XC);
    bf16*  xtT  = (bf16*)(ws + OFF_XTT);
    bf16*  WT   = (bf16*)(ws + OFF_WT);
    bf16*  Cb   = (bf16*)(ws + OFF_CB);
    bf16*  sl0  = (bf16*)(ws + OFF_XBF);         // reuse
    bf16*  sl1  = (bf16*)(ws + OFF_SLAB);
    bf16*  sl2  = (bf16*)(ws + OFF_SLAB + 4194304u);

    k_prep<<<2336, 256, 0, stream>>>(x, W, C, xbf, WT, Cb);
    k_proj<<<512, 256, 0, stream>>>(xbf, WT, Cb, bias, xt, xc, xtT);
    k_attn<<<2048, 256, 0, stream>>>(adj, xt, xc, xtT, sl0, sl1, sl2, out);
    k_reduce<<<2048, 256, 0, stream>>>(sl0, sl1, sl2, out);
}